// Round 6
// baseline (5002.504 us; speedup 1.0000x reference)
//
#include <hip/hip_runtime.h>

typedef unsigned short u16;
typedef __attribute__((ext_vector_type(8))) short short8;
typedef __attribute__((ext_vector_type(4))) float f32x4;

__device__ __forceinline__ float b2f(u16 u) {
  unsigned int i = ((unsigned int)u) << 16;
  return __builtin_bit_cast(float, i);
}
__device__ __forceinline__ u16 f2b(float f) {
  unsigned int i = __builtin_bit_cast(unsigned int, f);
  i += 0x7fffu + ((i >> 16) & 1u);   // RNE
  return (u16)(i >> 16);
}

// ---------------------------------------------------------------------------
// K1: KV projection, textbook fp32 tiled GEMM (unchanged from round 5).
// C[nb*8192][1536] = Xg @ Wkv^T (fp32 math), stored bf16 to
// KV[kv=2][bl][h=12][s=8192][d=64].
// ---------------------------------------------------------------------------
__global__ __launch_bounds__(256) void kv_gemm_simple(const float* __restrict__ Xg,
                                                      const float* __restrict__ W,
                                                      u16* __restrict__ KV, int nb) {
  __shared__ float Xs[32][36];
  __shared__ float Ws[32][36];
  const int tid = threadIdx.x;
  const int tx = tid & 15, ty = tid >> 4;
  const int bid = blockIdx.x;
  const int nt = bid % 48, mt = bid / 48;
  const int m0 = mt * 32, n0 = nt * 32;
  const int r = tid >> 3, c4 = (tid & 7) * 4;

  float acc[2][2] = {};

  for (int k0 = 0; k0 < 768; k0 += 32) {
    *(f32x4*)&Xs[r][c4] = *(const f32x4*)(Xg + (size_t)(m0 + r) * 768 + k0 + c4);
    *(f32x4*)&Ws[r][c4] = *(const f32x4*)(W + (size_t)(n0 + r) * 768 + k0 + c4);
    __syncthreads();
#pragma unroll
    for (int kk = 0; kk < 32; kk += 4) {
      f32x4 x0 = *(const f32x4*)&Xs[ty * 2][kk];
      f32x4 x1 = *(const f32x4*)&Xs[ty * 2 + 1][kk];
      f32x4 w0 = *(const f32x4*)&Ws[tx * 2][kk];
      f32x4 w1 = *(const f32x4*)&Ws[tx * 2 + 1][kk];
      acc[0][0] += x0.x * w0.x + x0.y * w0.y + x0.z * w0.z + x0.w * w0.w;
      acc[0][1] += x0.x * w1.x + x0.y * w1.y + x0.z * w1.z + x0.w * w1.w;
      acc[1][0] += x1.x * w0.x + x1.y * w0.y + x1.z * w0.z + x1.w * w0.w;
      acc[1][1] += x1.x * w1.x + x1.y * w1.y + x1.z * w1.z + x1.w * w1.w;
    }
    __syncthreads();
  }

#pragma unroll
  for (int i = 0; i < 2; ++i)
#pragma unroll
    for (int j = 0; j < 2; ++j) {
      int m = m0 + ty * 2 + i;
      int f = n0 + tx * 2 + j;
      int kvsel = f >= 768 ? 1 : 0;
      int h = (f - kvsel * 768) >> 6;
      int d = f & 63;
      int bl = m >> 13, s = m & 8191;
      KV[((size_t)(kvsel * nb + bl) * 12 + h) * (8192 * 64) + (size_t)s * 64 + d] =
          f2b(acc[i][j]);
    }
}

// ---------------------------------------------------------------------------
// K2: Q projection (fp32), scale 0.125 folded in. (unchanged)
// ---------------------------------------------------------------------------
__global__ __launch_bounds__(256) void q_proj(const float* __restrict__ X,
                                              const float* __restrict__ Wq,
                                              float* __restrict__ Q) {
  __shared__ float xs[768];
  const int bid = blockIdx.x;
  const int rrow = bid / 3, cg = bid % 3;
  const int b = rrow >> 2, s = rrow & 3;
  const float* xrow = X + ((size_t)b * 8192 + s) * 768;
  const int t = threadIdx.x;
  if (t < 192) *(f32x4*)&xs[t * 4] = *(const f32x4*)(xrow + t * 4);
  __syncthreads();
  const int c = cg * 256 + t;
  const float* wrow = Wq + (size_t)c * 768;
  float acc = 0.f;
#pragma unroll 8
  for (int jj = 0; jj < 192; ++jj) {
    f32x4 v = *(const f32x4*)(wrow + jj * 4);
    acc += v.x * xs[jj * 4] + v.y * xs[jj * 4 + 1] + v.z * xs[jj * 4 + 2] +
           v.w * xs[jj * 4 + 3];
  }
  Q[(size_t)rrow * 768 + c] = acc * 0.125f;
}

// ---------------------------------------------------------------------------
// K3: textbook attention, full softmax in LDS. (unchanged)
// ---------------------------------------------------------------------------
__global__ __launch_bounds__(256) void attn_simple(const u16* __restrict__ KV,
                                                   const float* __restrict__ Q,
                                                   float* __restrict__ Att,
                                                   int b0, int nb) {
  __shared__ float sc[8192];
  __shared__ float red[256];
  __shared__ float qsh[64];
  __shared__ float osum[4][64];
  const int tid = threadIdx.x;
  const int bid = blockIdx.x;
  const int x = bid & 3;
  const int rem = bid >> 2;
  const int h = rem % 12, bl = rem / 12;
  const int b = b0 + bl;

  if (tid < 64) qsh[tid] = Q[(size_t)(b * 4 + x) * 768 + h * 64 + tid];
  __syncthreads();

  const u16* Kb = KV + (size_t)(bl * 12 + h) * (8192 * 64);
  const u16* Vb = KV + (size_t)((nb + bl) * 12 + h) * (8192 * 64);

  float lmax = -__builtin_inff();
  for (int y = tid; y < 8192; y += 256) {
    const u16* kr = Kb + (size_t)y * 64;
    float s = 0.f;
#pragma unroll
    for (int jj = 0; jj < 8; ++jj) {
      short8 k8 = *(const short8*)(kr + jj * 8);
#pragma unroll
      for (int e = 0; e < 8; ++e) s += b2f((u16)k8[e]) * qsh[jj * 8 + e];
    }
    sc[y] = s;
    lmax = fmaxf(lmax, s);
  }
  red[tid] = lmax;
  __syncthreads();
  for (int off = 128; off; off >>= 1) {
    if (tid < off) red[tid] = fmaxf(red[tid], red[tid + off]);
    __syncthreads();
  }
  const float M = red[0];
  __syncthreads();

  float lsum = 0.f;
  for (int y = tid; y < 8192; y += 256) {
    float p = __expf(sc[y] - M);
    sc[y] = p;
    lsum += p;
  }
  red[tid] = lsum;
  __syncthreads();
  for (int off = 128; off; off >>= 1) {
    if (tid < off) red[tid] += red[tid + off];
    __syncthreads();
  }
  const float L = red[0];

  const int g = tid >> 6, d = tid & 63;
  float o = 0.f;
  for (int y = g; y < 8192; y += 4) o += sc[y] * b2f(Vb[(size_t)y * 64 + d]);
  osum[g][d] = o;
  __syncthreads();
  if (tid < 64) {
    float t = osum[0][tid] + osum[1][tid] + osum[2][tid] + osum[3][tid];
    Att[(size_t)(b * 4 + x) * 768 + h * 64 + tid] = t / L;
  }
}

// ---------------------------------------------------------------------------
// K4: output projection + bias. *** CHANGED: output stored as FP32 ***
// Out[32][768] fp32 = Att @ Wo^T + bo.  grid 96.
// ---------------------------------------------------------------------------
__global__ __launch_bounds__(256) void out_proj(const float* __restrict__ Att,
                                               const float* __restrict__ Wo,
                                               const float* __restrict__ Bo,
                                               float* __restrict__ Out) {
  __shared__ float xs[768];
  const int bid = blockIdx.x;
  const int rrow = bid / 3, cg = bid % 3;
  const int t = threadIdx.x;
  if (t < 192) *(f32x4*)&xs[t * 4] = *(const f32x4*)(Att + (size_t)rrow * 768 + t * 4);
  __syncthreads();
  const int c = cg * 256 + t;
  const float* wrow = Wo + (size_t)c * 768;
  float acc = 0.f;
#pragma unroll 8
  for (int jj = 0; jj < 192; ++jj) {
    f32x4 v = *(const f32x4*)(wrow + jj * 4);
    acc += v.x * xs[jj * 4] + v.y * xs[jj * 4 + 1] + v.z * xs[jj * 4 + 2] +
           v.w * xs[jj * 4 + 3];
  }
  acc += Bo[c];
  Out[(size_t)rrow * 768 + c] = acc;   // fp32 store — the one changed variable
}

// ---------------------------------------------------------------------------
extern "C" void kernel_launch(void* const* d_in, const int* in_sizes, int n_in,
                              void* d_out, int out_size, void* d_ws, size_t ws_size,
                              hipStream_t stream) {
  const float* X = (const float*)d_in[0];    // [8,8192,768] fp32
  const float* Wkv = (const float*)d_in[1];  // [1536,768] fp32
  const float* Wq = (const float*)d_in[2];   // [768,768] fp32
  const float* Wo = (const float*)d_in[3];   // [768,768] fp32
  const float* Bo = (const float*)d_in[4];   // [768] fp32
  float* Out = (float*)d_out;                // [8,4,768] fp32

  char* ws = (char*)d_ws;
  float* Q = (float*)ws;                     //  98,304 B
  float* Att = (float*)(ws + 98304);         //  98,304 B
  const size_t tail = 262144;
  u16* KV = (u16*)(ws + tail);

  const size_t kvPerBatch = 2ull * 12 * 8192 * 64 * 2;  // 25,165,824 B
  int nb = 8;
  while (nb > 1 && tail + (size_t)nb * kvPerBatch > ws_size) nb >>= 1;
  const int groups = 8 / nb;

  hipLaunchKernelGGL(q_proj, dim3(96), dim3(256), 0, stream, X, Wq, Q);
  for (int g = 0; g < groups; ++g) {
    const int b0 = g * nb;
    hipLaunchKernelGGL(kv_gemm_simple, dim3(nb * 12288), dim3(256), 0, stream,
                       X + (size_t)b0 * 8192 * 768, Wkv, KV, nb);
    hipLaunchKernelGGL(attn_simple, dim3(nb * 48), dim3(256), 0, stream,
                       KV, Q, Att, b0, nb);
  }
  hipLaunchKernelGGL(out_proj, dim3(96), dim3(256), 0, stream, Att, Wo, Bo, Out);
}